// Round 1
// baseline (208.894 us; speedup 1.0000x reference)
//
#include <hip/hip_runtime.h>

// Problem constants (match reference)
#define V_ 100000
#define D_ 256
#define M_ 4096
#define C_ 4096
#define L_ 32
#define ROWS_MEMS (M_ + 1)          // 4097 rows in mems_enc (mems + xs_emb)
#define NTASK (1 + M_ + 1 + C_)     // 8194 encode row-tasks

// ---------------------------------------------------------------------------
// K1: encode all rows. One 64-lane wave per row, 4 rows per 256-thread block.
// out row = sum_l (w_l / ||w||) * lt[tok_l, :]
// ---------------------------------------------------------------------------
__global__ __launch_bounds__(256) void encode_all(
    const int* __restrict__ xs, const int* __restrict__ mems,
    const int* __restrict__ ys, const int* __restrict__ cands,
    const float* __restrict__ lt, const float* __restrict__ freqs,
    float* __restrict__ mems_enc,   // [4097, 256]; row 4096 = xs_emb
    float* __restrict__ out_ys)     // d_out second half: [4097, 256]
{
    const int wave = threadIdx.x >> 6;
    const int lane = threadIdx.x & 63;
    const int rt = blockIdx.x * 4 + wave;
    if (rt >= NTASK) return;

    const int* tok_ptr;
    float* dst;
    if (rt == 0) {                       // xs -> mems_enc row 4096
        tok_ptr = xs;
        dst = mems_enc + (size_t)M_ * D_;
    } else if (rt <= M_) {               // mems row rt-1
        tok_ptr = mems + (size_t)(rt - 1) * L_;
        dst = mems_enc + (size_t)(rt - 1) * D_;
    } else if (rt == M_ + 1) {           // ys -> out_ys row 0
        tok_ptr = ys;
        dst = out_ys;
    } else {                             // cands row -> out_ys rows 1..4096
        const int c = rt - (M_ + 2);
        tok_ptr = cands + (size_t)c * L_;
        dst = out_ys + (size_t)(c + 1) * D_;
    }

    int tok = 0;
    float w = 0.0f;
    if (lane < L_) {
        tok = tok_ptr[lane];
        w = freqs[tok];
    }
    // ||w||^2 across the wave (lanes >= L_ contribute 0)
    float s = w * w;
    #pragma unroll
    for (int off = 32; off >= 1; off >>= 1) s += __shfl_down(s, off, 64);
    const float norm = sqrtf(__shfl(s, 0, 64));
    const float wn = w / norm;           // freqs > 0 -> norm > 0

    const int d0 = lane * 4;             // 64 lanes x 4 dims = 256
    float4 acc = make_float4(0.f, 0.f, 0.f, 0.f);
    #pragma unroll
    for (int l = 0; l < L_; ++l) {
        const int t = __shfl(tok, l, 64);
        const float wl = __shfl(wn, l, 64);
        const float4 v = *reinterpret_cast<const float4*>(lt + (size_t)t * D_ + d0);
        acc.x += wl * v.x;
        acc.y += wl * v.y;
        acc.z += wl * v.z;
        acc.w += wl * v.w;
    }
    *reinterpret_cast<float4*>(dst + d0) = acc;
}

// ---------------------------------------------------------------------------
// K2: per-row dot with xs_emb and squared norm. One 256-thread block per row.
// ---------------------------------------------------------------------------
__global__ __launch_bounds__(256) void dots_kernel(
    const float* __restrict__ enc, float* __restrict__ dots,
    float* __restrict__ norms2)
{
    __shared__ float sp[4], sq[4];
    const int i = blockIdx.x;
    const int t = threadIdx.x;
    const float r = enc[(size_t)i * D_ + t];
    const float x = enc[(size_t)M_ * D_ + t];
    float p = r * x;
    float q = r * r;
    #pragma unroll
    for (int off = 32; off >= 1; off >>= 1) {
        p += __shfl_down(p, off, 64);
        q += __shfl_down(q, off, 64);
    }
    const int wave = t >> 6, lane = t & 63;
    if (lane == 0) { sp[wave] = p; sq[wave] = q; }
    __syncthreads();
    if (t == 0) {
        dots[i]   = sp[0] + sp[1] + sp[2] + sp[3];
        norms2[i] = sq[0] + sq[1] + sq[2] + sq[3];
    }
}

// ---------------------------------------------------------------------------
// K3: softmax over the 4097 cosine sims. Single 1024-thread block.
// cos_i = dots[i] / (max(||xs||,eps) * max(||row_i||,eps))
// ---------------------------------------------------------------------------
__global__ __launch_bounds__(1024) void softmax_kernel(
    const float* __restrict__ dots, const float* __restrict__ norms2,
    float* __restrict__ att)
{
    __shared__ float red[16];
    const int t = threadIdx.x;
    const int wave = t >> 6, lane = t & 63;

    const float an = fmaxf(sqrtf(norms2[M_]), 1e-8f);

    float cosv[5];
    int cnt = 0;
    float mx = -1e30f;
    for (int i = t; i < ROWS_MEMS; i += 1024) {
        const float bn = fmaxf(sqrtf(norms2[i]), 1e-8f);
        const float c = dots[i] / (an * bn);
        cosv[cnt++] = c;
        mx = fmaxf(mx, c);
    }
    // block max
    #pragma unroll
    for (int off = 32; off >= 1; off >>= 1) mx = fmaxf(mx, __shfl_down(mx, off, 64));
    if (lane == 0) red[wave] = mx;
    __syncthreads();
    if (t < 16) {
        float m = red[t];
        #pragma unroll
        for (int off = 8; off >= 1; off >>= 1) m = fmaxf(m, __shfl_down(m, off, 16));
        if (t == 0) red[0] = m;
    }
    __syncthreads();
    mx = red[0];
    __syncthreads();

    // exp + block sum
    float s = 0.f;
    for (int k = 0; k < cnt; ++k) { cosv[k] = expf(cosv[k] - mx); s += cosv[k]; }
    #pragma unroll
    for (int off = 32; off >= 1; off >>= 1) s += __shfl_down(s, off, 64);
    if (lane == 0) red[wave] = s;
    __syncthreads();
    if (t < 16) {
        float m = red[t];
        #pragma unroll
        for (int off = 8; off >= 1; off >>= 1) m += __shfl_down(m, off, 16);
        if (t == 0) red[0] = m;
    }
    __syncthreads();
    const float inv = 1.0f / red[0];

    cnt = 0;
    for (int i = t; i < ROWS_MEMS; i += 1024) att[i] = cosv[cnt++] * inv;
}

// ---------------------------------------------------------------------------
// K4: lhs[d] = sum_i att[i] * enc[i][d]  (split-K over i, atomic combine)
// ---------------------------------------------------------------------------
__global__ __launch_bounds__(256) void lhs_kernel(
    const float* __restrict__ enc, const float* __restrict__ att,
    float* __restrict__ lhs)
{
    const int d = threadIdx.x;
    const int i0 = blockIdx.x * 64;
    const int i1 = min(i0 + 64, ROWS_MEMS);
    float acc = 0.f;
    for (int i = i0; i < i1; ++i) acc += att[i] * enc[(size_t)i * D_ + d];
    atomicAdd(&lhs[d], acc);
}

// ---------------------------------------------------------------------------
// K5: tile lhs into out_xs rows 0..4096
// ---------------------------------------------------------------------------
__global__ __launch_bounds__(256) void tile_kernel(
    const float* __restrict__ lhs, float* __restrict__ out_xs)
{
    out_xs[(size_t)blockIdx.x * D_ + threadIdx.x] = lhs[threadIdx.x];
}

extern "C" void kernel_launch(void* const* d_in, const int* in_sizes, int n_in,
                              void* d_out, int out_size, void* d_ws, size_t ws_size,
                              hipStream_t stream) {
    const int*   xs    = (const int*)d_in[0];
    const int*   mems  = (const int*)d_in[1];
    const int*   ys    = (const int*)d_in[2];
    const int*   cands = (const int*)d_in[3];
    const float* lt    = (const float*)d_in[4];
    const float* freqs = (const float*)d_in[5];

    float* out    = (float*)d_out;
    float* out_xs = out;                                  // [4097, 256]
    float* out_ys = out + (size_t)ROWS_MEMS * D_;         // [4097, 256]

    // workspace layout (floats): enc[4097*256] | dots[4097] | norms2[4097] | att[4097] | lhs[256]
    float* enc    = (float*)d_ws;
    float* dots   = enc + (size_t)ROWS_MEMS * D_;
    float* norms2 = dots + ROWS_MEMS;
    float* att    = norms2 + ROWS_MEMS;
    float* lhs    = att + ROWS_MEMS;

    hipMemsetAsync(lhs, 0, D_ * sizeof(float), stream);

    encode_all<<<(NTASK + 3) / 4, 256, 0, stream>>>(xs, mems, ys, cands, lt, freqs,
                                                    enc, out_ys);
    dots_kernel<<<ROWS_MEMS, 256, 0, stream>>>(enc, dots, norms2);
    softmax_kernel<<<1, 1024, 0, stream>>>(dots, norms2, att);
    lhs_kernel<<<(ROWS_MEMS + 63) / 64, 256, 0, stream>>>(enc, att, lhs);
    tile_kernel<<<ROWS_MEMS, 256, 0, stream>>>(lhs, out_xs);
}